// Round 1
// baseline (3339.985 us; speedup 1.0000x reference)
//
#include <hip/hip_runtime.h>
#include <math.h>

#define EPS 1e-5f
#define SLOPE 0.2f

__device__ __forceinline__ float lrelu(float x){ return x >= 0.f ? x : SLOPE*x; }

// ---------- bilinear x2 upsample, align_corners=True: [B,256,32,32]->[B,256,64,64]
__global__ void k_up(const float* __restrict__ x, float* __restrict__ u){
  int idx = blockIdx.x*256 + threadIdx.x;          // 4*256*64*64 total
  int ow = idx & 63; int oh = (idx>>6)&63; int bc = idx>>12;
  const float st = 31.0f/63.0f;
  float fh = oh*st, fw = ow*st;
  int h0 = (int)fh; int w0 = (int)fw;
  float wh = fh - (float)h0, ww = fw - (float)w0;
  int h1 = min(h0+1,31), w1 = min(w0+1,31);
  const float* xp = x + (size_t)bc*1024;
  float a = xp[h0*32+w0], b_ = xp[h0*32+w1], c = xp[h1*32+w0], d = xp[h1*32+w1];
  float top = a + (b_-a)*ww;
  float bot = c + (d-c)*ww;
  u[idx] = top + (bot-top)*wh;
}

// ---------- direct 3x3 conv (pad 1) + optional bias + BN + LReLU
// one block = one (b, co, 256-pixel tile); weights for co staged in LDS
template<int CIN>
__global__ void k_conv3(const float* __restrict__ in, const float* __restrict__ W,
                        const float* __restrict__ bias,
                        const float* __restrict__ g, const float* __restrict__ be,
                        const float* __restrict__ mm, const float* __restrict__ vv,
                        float* __restrict__ out, int COUT){
  int blk = blockIdx.x;
  int tile = blk & 15;
  int co = (blk>>4) & (COUT-1);
  int b  = blk >> 11;                 // 16*COUT = 2048 blocks per batch (COUT=128)
  __shared__ float lw[CIN*9];
  for(int i=threadIdx.x;i<CIN*9;i+=256) lw[i] = W[(size_t)co*CIN*9 + i];
  __syncthreads();
  int p = tile*256 + threadIdx.x;
  int h = p>>6, w = p&63;
  bool vh0 = h>0, vh2 = h<63, vw0 = w>0, vw2 = w<63;
  const float* ip = in + ((size_t)b*CIN)*4096 + p;
  float acc = 0.f;
  #pragma unroll 4
  for(int ci=0; ci<CIN; ++ci){
    const float* q = ip + (size_t)ci*4096;
    const float* wp = lw + ci*9;
    float x00 = (vh0&&vw0)? q[-65]:0.f;
    float x01 = (vh0)?      q[-64]:0.f;
    float x02 = (vh0&&vw2)? q[-63]:0.f;
    float x10 = (vw0)?      q[-1]:0.f;
    float x11 =             q[0];
    float x12 = (vw2)?      q[1]:0.f;
    float x20 = (vh2&&vw0)? q[63]:0.f;
    float x21 = (vh2)?      q[64]:0.f;
    float x22 = (vh2&&vw2)? q[65]:0.f;
    acc += wp[0]*x00 + wp[1]*x01 + wp[2]*x02
         + wp[3]*x10 + wp[4]*x11 + wp[5]*x12
         + wp[6]*x20 + wp[7]*x21 + wp[8]*x22;
  }
  float scale = g[co] * rsqrtf(vv[co]+EPS);
  float bsv = bias ? bias[co] : 0.f;
  float shift = bsv*scale + be[co] - mm[co]*scale;
  out[((size_t)b*COUT + co)*4096 + p] = lrelu(acc*scale + shift);
}

// ---------- q = Wq@x2 + bq  -> [B,N,64]
__global__ void k_q(const float* __restrict__ x2, const float* __restrict__ Wq,
                    const float* __restrict__ bq, float* __restrict__ q){
  __shared__ float lw[128*64];                 // [c][o]
  for(int i=threadIdx.x;i<128*64;i+=256){ int c=i>>6, o=i&63; lw[c*64+o]=Wq[o*128+c]; }
  __syncthreads();
  int o = threadIdx.x & 63;
  int mi = threadIdx.x >> 6;
  int m = (blockIdx.x & 1023)*4 + mi;
  int b = blockIdx.x >> 10;
  const float* xp = x2 + ((size_t)b*128)*4096 + m;
  float acc = bq[o];
  #pragma unroll 8
  for(int c=0;c<128;++c) acc += lw[c*64+o]*xp[(size_t)c*4096];
  q[((size_t)b*4096 + m)*64 + o] = acc;
}

// ---------- k = Wk@x2 + bk  -> [B,64,N]
__global__ void k_k(const float* __restrict__ x2, const float* __restrict__ Wk,
                    const float* __restrict__ bk, float* __restrict__ kk){
  __shared__ float lw[128*64];                 // [c][o]
  for(int i=threadIdx.x;i<128*64;i+=256){ int c=i>>6, o=i&63; lw[c*64+o]=Wk[o*128+c]; }
  __syncthreads();
  int n = (blockIdx.x & 63)*64 + (threadIdx.x & 63);
  int o = ((blockIdx.x>>6)&15)*4 + (threadIdx.x>>6);
  int b = blockIdx.x >> 10;
  const float* xp = x2 + ((size_t)b*128)*4096 + n;
  float acc = bk[o];
  #pragma unroll 8
  for(int c=0;c<128;++c) acc += lw[c*64+o]*xp[(size_t)c*4096];
  kk[((size_t)b*64 + o)*4096 + n] = acc;
}

// ---------- vT = (Wv@x2 + bv)^T -> [B,N,128]
__global__ void k_v(const float* __restrict__ x2, const float* __restrict__ Wv,
                    const float* __restrict__ bv, float* __restrict__ vt){
  __shared__ float lw[128*128];                // [cc][c]  (64 KiB)
  for(int i=threadIdx.x;i<128*128;i+=256){ int cc=i>>7, c=i&127; lw[cc*128+c]=Wv[c*128+cc]; }
  __syncthreads();
  int c = threadIdx.x & 127;
  int ni = threadIdx.x >> 7;
  int n = (blockIdx.x & 2047)*2 + ni;
  int b = blockIdx.x >> 11;
  const float* xp = x2 + ((size_t)b*128)*4096 + n;
  float acc = bv[c];
  #pragma unroll 8
  for(int cc=0;cc<128;++cc) acc += lw[cc*128+c]*xp[(size_t)cc*4096];
  vt[((size_t)b*4096 + n)*128 + c] = acc;
}

// ---------- flash attention + residual(+x2) + residual(+identity) + lrelu
// one wave per query row m; 4 waves per block
__global__ void k_attn(const float* __restrict__ q, const float* __restrict__ kk,
                       const float* __restrict__ vt, const float* __restrict__ x2,
                       const float* __restrict__ idb, float* __restrict__ out){
  int wid = threadIdx.x >> 6;
  int lane = threadIdx.x & 63;
  int row = blockIdx.x*4 + wid;               // 0 .. B*4096-1
  int b = row >> 12;
  int m = row & 4095;
  float qreg = q[(size_t)row*64 + lane];
  const float* kb = kk + (size_t)b*64*4096;
  const float* vb = vt + (size_t)b*4096*128;
  float mrun = -1e30f, lrun = 0.f, acc0 = 0.f, acc1 = 0.f;
  for(int ch=0; ch<64; ++ch){
    int n = ch*64 + lane;
    float s = 0.f;
    const float* kp = kb + n;
    #pragma unroll
    for(int o=0;o<64;++o) s += __shfl(qreg,o) * kp[(size_t)o*4096];
    float cm = s;
    #pragma unroll
    for(int d=32;d>=1;d>>=1) cm = fmaxf(cm, __shfl_xor(cm,d));
    float mnew = fmaxf(mrun, cm);
    float p = __expf(s - mnew);
    float alpha = __expf(mrun - mnew);
    float ps = p;
    #pragma unroll
    for(int d=32;d>=1;d>>=1) ps += __shfl_xor(ps,d);
    lrun = lrun*alpha + ps;
    acc0 *= alpha; acc1 *= alpha;
    const float* vp = vb + (size_t)ch*64*128;
    #pragma unroll 8
    for(int j=0;j<64;++j){
      float pj = __shfl(p,j);
      acc0 += pj * vp[j*128 + lane];
      acc1 += pj * vp[j*128 + 64 + lane];
    }
    mrun = mnew;
  }
  float inv = 1.f/lrun;
  size_t base = ((size_t)b*128)*4096 + m;
  float o0 = acc0*inv + x2[base + (size_t)lane*4096]      + idb[base + (size_t)lane*4096];
  float o1 = acc1*inv + x2[base + (size_t)(64+lane)*4096] + idb[base + (size_t)(64+lane)*4096];
  out[base + (size_t)lane*4096]      = lrelu(o0);
  out[base + (size_t)(64+lane)*4096] = lrelu(o1);
}

extern "C" void kernel_launch(void* const* d_in, const int* in_sizes, int n_in,
                              void* d_out, int out_size, void* d_ws, size_t ws_size,
                              hipStream_t stream) {
  const float* x    = (const float*)d_in[0];
  const float* W_up = (const float*)d_in[1];
  const float* b_up = (const float*)d_in[2];
  const float* g0   = (const float*)d_in[3];
  const float* be0  = (const float*)d_in[4];
  const float* m0   = (const float*)d_in[5];
  const float* v0   = (const float*)d_in[6];
  const float* W_r0 = (const float*)d_in[7];
  const float* g1   = (const float*)d_in[8];
  const float* be1  = (const float*)d_in[9];
  const float* m1   = (const float*)d_in[10];
  const float* v1   = (const float*)d_in[11];
  const float* W_r1 = (const float*)d_in[12];
  const float* g2   = (const float*)d_in[13];
  const float* be2  = (const float*)d_in[14];
  const float* m2   = (const float*)d_in[15];
  const float* v2   = (const float*)d_in[16];
  const float* Wq   = (const float*)d_in[17];
  const float* bq   = (const float*)d_in[18];
  const float* Wk   = (const float*)d_in[19];
  const float* bk   = (const float*)d_in[20];
  const float* Wv   = (const float*)d_in[21];
  const float* bv   = (const float*)d_in[22];

  float* ws  = (float*)d_ws;
  float* u   = ws;                     // 4*256*4096 = 4,194,304 floats
  float* idb = ws + 4194304;           // 2,097,152
  float* x1  = idb + 2097152;          // 2,097,152
  float* x2  = u;                      // alias (u dead after conv_up)
  float* qb  = u + 2097152;            // 1,048,576
  float* kb  = qb + 1048576;           // 1,048,576
  float* vt  = x1;                     // alias (x1 dead after conv_r1)
  float* out = (float*)d_out;

  // 1. upsample
  k_up<<<16384, 256, 0, stream>>>(x, u);
  // 2. conv_up + b_up + bn0 + lrelu -> identity
  k_conv3<256><<<8192, 256, 0, stream>>>(u, W_up, b_up, g0, be0, m0, v0, idb, 128);
  // 3. conv_r0 + bn1 + lrelu
  k_conv3<128><<<8192, 256, 0, stream>>>(idb, W_r0, nullptr, g1, be1, m1, v1, x1, 128);
  // 4. conv_r1 + bn2 + lrelu -> x2 (attn input)
  k_conv3<128><<<8192, 256, 0, stream>>>(x1, W_r1, nullptr, g2, be2, m2, v2, x2, 128);
  // 5. q,k,v
  k_q<<<4096, 256, 0, stream>>>(x2, Wq, bq, qb);
  k_k<<<4096, 256, 0, stream>>>(x2, Wk, bk, kb);
  k_v<<<8192, 256, 0, stream>>>(x2, Wv, bv, vt);
  // 6. attention + residuals + lrelu
  k_attn<<<4096, 256, 0, stream>>>(qb, kb, vt, x2, idb, out);
}

// Round 2
// 1792.531 us; speedup vs baseline: 1.8633x; 1.8633x over previous
//
#include <hip/hip_runtime.h>
#include <math.h>

#define EPS 1e-5f
#define SLOPE 0.2f

typedef unsigned short u16;
typedef unsigned int u32;
typedef __attribute__((ext_vector_type(4))) float f32x4;
typedef __attribute__((ext_vector_type(8))) short s16x8;

__device__ __forceinline__ float lrelu(float x){ return x >= 0.f ? x : SLOPE*x; }

// f32 -> bf16 bits, round-to-nearest-even
__device__ __forceinline__ u16 f2b(float x){
  u32 u = __float_as_uint(x);
  u32 r = (u + 0x7FFFu + ((u >> 16) & 1u)) >> 16;
  return (u16)r;
}

// ---------- bilinear x2 upsample, align_corners=True: [B,256,32,32]->[B,256,64,64]
__global__ void k_up(const float* __restrict__ x, float* __restrict__ u){
  int idx = blockIdx.x*256 + threadIdx.x;
  int ow = idx & 63; int oh = (idx>>6)&63; int bc = idx>>12;
  const float st = 31.0f/63.0f;
  float fh = oh*st, fw = ow*st;
  int h0 = (int)fh; int w0 = (int)fw;
  float wh = fh - (float)h0, ww = fw - (float)w0;
  int h1 = min(h0+1,31), w1 = min(w0+1,31);
  const float* xp = x + (size_t)bc*1024;
  float a = xp[h0*32+w0], b_ = xp[h0*32+w1], c = xp[h1*32+w0], d = xp[h1*32+w1];
  float top = a + (b_-a)*ww;
  float bot = c + (d-c)*ww;
  u[idx] = top + (bot-top)*wh;
}

// ---------- direct 3x3 conv (pad 1) + optional bias + BN + LReLU
template<int CIN>
__global__ void k_conv3(const float* __restrict__ in, const float* __restrict__ W,
                        const float* __restrict__ bias,
                        const float* __restrict__ g, const float* __restrict__ be,
                        const float* __restrict__ mm, const float* __restrict__ vv,
                        float* __restrict__ out, int COUT){
  int blk = blockIdx.x;
  int tile = blk & 15;
  int co = (blk>>4) & (COUT-1);
  int b  = blk >> 11;
  __shared__ float lw[CIN*9];
  for(int i=threadIdx.x;i<CIN*9;i+=256) lw[i] = W[(size_t)co*CIN*9 + i];
  __syncthreads();
  int p = tile*256 + threadIdx.x;
  int h = p>>6, w = p&63;
  bool vh0 = h>0, vh2 = h<63, vw0 = w>0, vw2 = w<63;
  const float* ip = in + ((size_t)b*CIN)*4096 + p;
  float acc = 0.f;
  #pragma unroll 4
  for(int ci=0; ci<CIN; ++ci){
    const float* q = ip + (size_t)ci*4096;
    const float* wp = lw + ci*9;
    float x00 = (vh0&&vw0)? q[-65]:0.f;
    float x01 = (vh0)?      q[-64]:0.f;
    float x02 = (vh0&&vw2)? q[-63]:0.f;
    float x10 = (vw0)?      q[-1]:0.f;
    float x11 =             q[0];
    float x12 = (vw2)?      q[1]:0.f;
    float x20 = (vh2&&vw0)? q[63]:0.f;
    float x21 = (vh2)?      q[64]:0.f;
    float x22 = (vh2&&vw2)? q[65]:0.f;
    acc += wp[0]*x00 + wp[1]*x01 + wp[2]*x02
         + wp[3]*x10 + wp[4]*x11 + wp[5]*x12
         + wp[6]*x20 + wp[7]*x21 + wp[8]*x22;
  }
  float scale = g[co] * rsqrtf(vv[co]+EPS);
  float bsv = bias ? bias[co] : 0.f;
  float shift = bsv*scale + be[co] - mm[co]*scale;
  out[((size_t)b*COUT + co)*4096 + p] = lrelu(acc*scale + shift);
}

// ---------- q or k projection -> [B,N,64] bf16 (row-major, 64 contiguous)
__global__ void k_qk(const float* __restrict__ x2, const float* __restrict__ W,
                     const float* __restrict__ bias, u16* __restrict__ outb){
  __shared__ float lw[128*64];                 // [c][o]
  for(int i=threadIdx.x;i<128*64;i+=256){ int c=i>>6, o=i&63; lw[c*64+o]=W[o*128+c]; }
  __syncthreads();
  int o = threadIdx.x & 63;
  int mi = threadIdx.x >> 6;
  int m = (blockIdx.x & 1023)*4 + mi;
  int b = blockIdx.x >> 10;
  const float* xp = x2 + ((size_t)b*128)*4096 + m;
  float acc = bias[o];
  #pragma unroll 8
  for(int c=0;c<128;++c) acc += lw[c*64+o]*xp[(size_t)c*4096];
  outb[((size_t)b*4096 + m)*64 + o] = f2b(acc);
}

// ---------- v projection -> [B,128,4096] bf16 (c-major)
__global__ void k_v2(const float* __restrict__ x2, const float* __restrict__ Wv,
                     const float* __restrict__ bv, u16* __restrict__ vbf){
  __shared__ float lw[128*128];                // [cc][c]  (64 KiB)
  for(int i=threadIdx.x;i<128*128;i+=256){ int cc=i>>7, c=i&127; lw[cc*128+c]=Wv[c*128+cc]; }
  __syncthreads();
  int n = (blockIdx.x & 63)*64 + (threadIdx.x & 63);
  int c = ((blockIdx.x>>6)&31)*4 + (threadIdx.x>>6);
  int b = blockIdx.x >> 11;
  const float* xp = x2 + ((size_t)b*128)*4096 + n;
  float acc = bv[c];
  #pragma unroll 8
  for(int cc=0;cc<128;++cc) acc += lw[cc*128+c]*xp[(size_t)cc*4096];
  vbf[((size_t)b*128 + c)*4096 + n] = f2b(acc);
}

// ---------- MFMA flash attention + residual(+x2) + residual(+identity) + lrelu
// block = 4 waves; wave handles 16 q-rows; KV tiles of 64
__global__ __launch_bounds__(256) void k_fattn(
    const u16* __restrict__ qbf, const u16* __restrict__ kbf,
    const u16* __restrict__ vbf, const float* __restrict__ x2,
    const float* __restrict__ idb, float* __restrict__ out){
  __shared__ u16 pl[4][1024];       // per-wave P [16 m][64 n] bf16, XOR-swizzled
  int wid = threadIdx.x>>6, lane = threadIdx.x&63;
  int g = lane>>4, lr = lane&15;
  int b = blockIdx.x>>6, mt = blockIdx.x&63;
  int mbase = mt*64 + wid*16;

  // Q B-fragments: col m = lr, k = dk = kf*32 + g*8 + j  (contiguous 16B)
  const u16* qp = qbf + ((size_t)b*4096 + mbase + lr)*64 + g*8;
  s16x8 qf0 = *(const s16x8*)qp;
  s16x8 qf1 = *(const s16x8*)(qp + 32);

  f32x4 acc[8];
  #pragma unroll
  for(int i=0;i<8;++i) acc[i] = (f32x4)0.f;
  float mrun = -3.0e38f, lrun = 0.f;

  const u16* kb0 = kbf + (size_t)b*4096*64 + (size_t)lr*64 + g*8;
  const u16* vb0 = vbf + ((size_t)b*128 + lr)*4096 + g*8;
  u16* pw = pl[wid];
  u32 swz = ((u32)(lr & 7)) << 4;
  u32 wb[4];
  #pragma unroll
  for(int nf=0;nf<4;++nf) wb[nf] = ((u32)((lr*64 + nf*16 + g*4)*2)) ^ swz;
  u32 rb0 = ((u32)((lr*64 + g*8)*2)) ^ swz;
  u32 rb1 = ((u32)((lr*64 + 32 + g*8)*2)) ^ swz;

  for(int nt=0; nt<64; ++nt){
    // S^T tile [64 n][16 m]: mfma(A=K, B=Q)
    const u16* kp = kb0 + (size_t)nt*64*64;
    f32x4 sf[4];
    #pragma unroll
    for(int nf=0;nf<4;++nf){
      s16x8 ka0 = *(const s16x8*)(kp + nf*16*64);
      s16x8 ka1 = *(const s16x8*)(kp + nf*16*64 + 32);
      f32x4 z = (f32x4)0.f;
      z = __builtin_amdgcn_mfma_f32_16x16x32_bf16(ka0, qf0, z, 0, 0, 0);
      z = __builtin_amdgcn_mfma_f32_16x16x32_bf16(ka1, qf1, z, 0, 0, 0);
      sf[nf] = z;
    }
    // online softmax over n for column m = lr (per-lane scalar stats)
    float tm = -3.0e38f;
    #pragma unroll
    for(int nf=0;nf<4;++nf){
      #pragma unroll
      for(int r=0;r<4;++r) tm = fmaxf(tm, sf[nf][r]);
    }
    tm = fmaxf(tm, __shfl_xor(tm, 16));
    tm = fmaxf(tm, __shfl_xor(tm, 32));
    float mnew = fmaxf(mrun, tm);
    float alpha = __expf(mrun - mnew);
    float ps = 0.f;
    #pragma unroll
    for(int nf=0;nf<4;++nf){
      #pragma unroll
      for(int r=0;r<4;++r){ float p = __expf(sf[nf][r] - mnew); sf[nf][r] = p; ps += p; }
    }
    ps += __shfl_xor(ps, 16);
    ps += __shfl_xor(ps, 32);
    lrun = lrun*alpha + ps;
    mrun = mnew;
    #pragma unroll
    for(int i=0;i<8;++i) acc[i] *= alpha;
    // P -> LDS bf16 (wave-private, swizzled)
    #pragma unroll
    for(int nf=0;nf<4;++nf){
      u32 lo = (u32)f2b(sf[nf][0]) | ((u32)f2b(sf[nf][1]) << 16);
      u32 hi = (u32)f2b(sf[nf][2]) | ((u32)f2b(sf[nf][3]) << 16);
      uint2 wv; wv.x = lo; wv.y = hi;
      *(uint2*)((char*)pw + wb[nf]) = wv;
    }
    // P B-fragments: col m = lr, k = n = kf*32 + g*8 + j
    s16x8 pb0 = *(const s16x8*)((char*)pw + rb0);
    s16x8 pb1 = *(const s16x8*)((char*)pw + rb1);
    // O^T += V^T @ P^T : A = V^T chunk [16 c][32 n]
    const u16* vp = vb0 + nt*64;
    #pragma unroll
    for(int cf=0;cf<8;++cf){
      s16x8 va0 = *(const s16x8*)(vp + (size_t)cf*16*4096);
      s16x8 va1 = *(const s16x8*)(vp + (size_t)cf*16*4096 + 32);
      acc[cf] = __builtin_amdgcn_mfma_f32_16x16x32_bf16(va0, pb0, acc[cf], 0, 0, 0);
      acc[cf] = __builtin_amdgcn_mfma_f32_16x16x32_bf16(va1, pb1, acc[cf], 0, 0, 0);
    }
  }
  float inv = 1.f/lrun;
  size_t obase = ((size_t)b*128)*4096 + mbase + lr;
  #pragma unroll
  for(int cf=0;cf<8;++cf){
    #pragma unroll
    for(int r=0;r<4;++r){
      int c = cf*16 + g*4 + r;
      size_t o = obase + (size_t)c*4096;
      float val = acc[cf][r]*inv + x2[o] + idb[o];
      out[o] = lrelu(val);
    }
  }
}

extern "C" void kernel_launch(void* const* d_in, const int* in_sizes, int n_in,
                              void* d_out, int out_size, void* d_ws, size_t ws_size,
                              hipStream_t stream) {
  const float* x    = (const float*)d_in[0];
  const float* W_up = (const float*)d_in[1];
  const float* b_up = (const float*)d_in[2];
  const float* g0   = (const float*)d_in[3];
  const float* be0  = (const float*)d_in[4];
  const float* m0   = (const float*)d_in[5];
  const float* v0   = (const float*)d_in[6];
  const float* W_r0 = (const float*)d_in[7];
  const float* g1   = (const float*)d_in[8];
  const float* be1  = (const float*)d_in[9];
  const float* m1   = (const float*)d_in[10];
  const float* v1   = (const float*)d_in[11];
  const float* W_r1 = (const float*)d_in[12];
  const float* g2   = (const float*)d_in[13];
  const float* be2  = (const float*)d_in[14];
  const float* m2   = (const float*)d_in[15];
  const float* v2   = (const float*)d_in[16];
  const float* Wq   = (const float*)d_in[17];
  const float* bq   = (const float*)d_in[18];
  const float* Wk   = (const float*)d_in[19];
  const float* bk   = (const float*)d_in[20];
  const float* Wv   = (const float*)d_in[21];
  const float* bv   = (const float*)d_in[22];

  float* ws  = (float*)d_ws;
  float* u   = ws;                      // [0, 4194304)
  float* idb = ws + 4194304;            // [4194304, 6291456)
  float* x1  = ws + 6291456;            // [6291456, 8388608)
  float* x2  = u;                       // [0, 2097152)  (u dead after conv_up)
  u16*  qbf  = (u16*)(ws + 2097152);    // 1M u16
  u16*  kbf  = (u16*)(ws + 2621440);    // 1M u16
  u16*  vbf  = (u16*)(ws + 3145728);    // 2M u16
  float* out = (float*)d_out;

  // 1. upsample
  k_up<<<16384, 256, 0, stream>>>(x, u);
  // 2. conv_up + b_up + bn0 + lrelu -> identity
  k_conv3<256><<<8192, 256, 0, stream>>>(u, W_up, b_up, g0, be0, m0, v0, idb, 128);
  // 3. conv_r0 + bn1 + lrelu
  k_conv3<128><<<8192, 256, 0, stream>>>(idb, W_r0, nullptr, g1, be1, m1, v1, x1, 128);
  // 4. conv_r1 + bn2 + lrelu -> x2 (attn input)
  k_conv3<128><<<8192, 256, 0, stream>>>(x1, W_r1, nullptr, g2, be2, m2, v2, x2, 128);
  // 5. q,k -> [B,N,64] bf16 ; v -> [B,128,N] bf16
  k_qk<<<4096, 256, 0, stream>>>(x2, Wq, bq, qbf);
  k_qk<<<4096, 256, 0, stream>>>(x2, Wk, bk, kbf);
  k_v2<<<8192, 256, 0, stream>>>(x2, Wv, bv, vbf);
  // 6. MFMA flash attention + residuals + lrelu
  k_fattn<<<256, 256, 0, stream>>>(qbf, kbf, vbf, x2, idb, out);
}

// Round 3
// 369.401 us; speedup vs baseline: 9.0416x; 4.8525x over previous
//
#include <hip/hip_runtime.h>
#include <math.h>

#define EPS 1e-5f
#define SLOPE 0.2f

typedef unsigned short u16;
typedef unsigned int u32;
typedef __attribute__((ext_vector_type(4))) float f32x4;
typedef __attribute__((ext_vector_type(8))) short s16x8;
typedef __attribute__((ext_vector_type(4))) short s16x4;

__device__ __forceinline__ float lrelu(float x){ return x >= 0.f ? x : SLOPE*x; }

// f32 -> bf16 bits, round-to-nearest-even
__device__ __forceinline__ u16 f2b(float x){
  u32 u = __float_as_uint(x);
  u32 r = (u + 0x7FFFu + ((u >> 16) & 1u)) >> 16;
  return (u16)r;
}
__device__ __forceinline__ float b2f(short v){
  return __uint_as_float(((u32)(u16)v) << 16);
}

// ---------- NCHW f32 [4,256,32,32] -> NHWC bf16 [4,1024,256] (LDS transpose)
__global__ void k_tr(const float* __restrict__ x, u16* __restrict__ xh){
  __shared__ float t[32][33];
  int b = blockIdx.x>>8; int c0 = ((blockIdx.x>>5)&7)*32; int p0 = (blockIdx.x&31)*32;
  int tx = threadIdx.x&31, ty = threadIdx.x>>5;   // 32 x 8
  #pragma unroll
  for(int r=0;r<32;r+=8)
    t[ty+r][tx] = x[((size_t)(b*256 + c0+ty+r))*1024 + p0 + tx];
  __syncthreads();
  #pragma unroll
  for(int r=0;r<32;r+=8)
    xh[((size_t)(b*1024 + p0+ty+r))*256 + c0 + tx] = f2b(t[tx][ty+r]);
}

// ---------- bilinear x2 upsample (align_corners) NHWC bf16: [4,32,32,256]->[4,64,64,256]
__global__ void k_up8(const u16* __restrict__ xh, u16* __restrict__ u){
  int idx = blockIdx.x*256 + threadIdx.x;    // 524288 total (8 ch per thread)
  int cg = idx & 31;
  int ow = (idx>>5) & 63; int oh = (idx>>11)&63; int b = idx>>17;
  const float st = 31.0f/63.0f;
  float fh = oh*st, fw = ow*st;
  int h0=(int)fh, w0=(int)fw;
  float wh = fh-(float)h0, ww = fw-(float)w0;
  int h1=min(h0+1,31), w1=min(w0+1,31);
  const u16* xb = xh + ((size_t)b*1024)*256 + cg*8;
  s16x8 a = *(const s16x8*)(xb + (size_t)(h0*32+w0)*256);
  s16x8 bb= *(const s16x8*)(xb + (size_t)(h0*32+w1)*256);
  s16x8 c = *(const s16x8*)(xb + (size_t)(h1*32+w0)*256);
  s16x8 d = *(const s16x8*)(xb + (size_t)(h1*32+w1)*256);
  u16 o[8];
  #pragma unroll
  for(int j=0;j<8;++j){
    float top = b2f(a[j]) + (b2f(bb[j])-b2f(a[j]))*ww;
    float bot = b2f(c[j]) + (b2f(d[j])-b2f(c[j]))*ww;
    o[j] = f2b(top + (bot-top)*wh);
  }
  *(s16x8*)(u + (size_t)idx*8) = *(s16x8*)o;
}

// ---------- conv weight transform: OIHW f32 -> [co][tap*Cin+ci] bf16
template<int CIN>
__global__ void k_wconv(const float* __restrict__ W, u16* __restrict__ wt){
  int idx = blockIdx.x*256 + threadIdx.x;     // co*(9*CIN)+tap*CIN+ci
  int ci = idx & (CIN-1);
  int t2 = idx / CIN;
  int tap = t2 % 9;
  int co = t2 / 9;
  wt[idx] = f2b(W[((size_t)co*CIN + ci)*9 + tap]);
}

// ---------- projection weight transform
__global__ void k_wproj(const float* __restrict__ Wq, const float* __restrict__ Wk,
                        const float* __restrict__ Wv, u16* __restrict__ wqk,
                        u16* __restrict__ wv){
  int idx = blockIdx.x*256 + threadIdx.x;     // 32768
  if(idx < 16384){
    float v_ = idx < 8192 ? Wq[idx] : Wk[idx-8192];
    wqk[idx] = f2b(v_);
  } else {
    wv[idx-16384] = f2b(Wv[idx-16384]);
  }
}

// ---------- implicit-GEMM 3x3 conv (MFMA) + BN + LReLU, NHWC bf16
// wave: 32 px x 64 co; block 2 waves (64 px x 64 co); grid 64mt x 2nt x 4b = 512
template<int CIN>
__global__ __launch_bounds__(128) void k_cmfma(
    const u16* __restrict__ xin, const u16* __restrict__ wt,
    const float* __restrict__ bias,
    const float* __restrict__ g, const float* __restrict__ be,
    const float* __restrict__ mm, const float* __restrict__ vv,
    u16* __restrict__ out)
{
  constexpr int K = CIN*9;
  int blk = blockIdx.x;
  int mt = blk & 63;
  int nt = (blk>>6) & 1;
  int b  = blk >> 7;
  int wid = threadIdx.x>>6, lane = threadIdx.x&63;
  int gq = lane>>4, lr = lane&15;
  int g8 = gq*8;
  int mb = mt*64 + wid*32;
  int h = mb>>6, w0 = mb&63;
  int cob = nt*64;

  f32x4 acc[2][4];
  #pragma unroll
  for(int pf=0;pf<2;++pf)
    #pragma unroll
    for(int cf=0;cf<4;++cf) acc[pf][cf]=(f32x4)0.f;

  const u16* xb = xin + (size_t)b*4096*CIN;
  const u16* wr = wt + (size_t)(cob+lr)*K + g8;

  for(int dy=-1; dy<=1; ++dy){
    int hh = h+dy;
    if(hh<0 || hh>63) continue;
    #pragma unroll
    for(int dx=-1; dx<=1; ++dx){
      int tap = (dy+1)*3 + (dx+1);
      const u16* wtap = wr + tap*CIN;
      const u16* ar[2]; bool av[2];
      #pragma unroll
      for(int pf=0;pf<2;++pf){
        int ww = w0 + pf*16 + lr + dx;
        av[pf] = (ww>=0)&&(ww<64);
        int wc = ww<0?0:(ww>63?63:ww);
        ar[pf] = xb + ((size_t)hh*64 + wc)*CIN + g8;
      }
      #pragma unroll
      for(int kc=0;kc<CIN/32;++kc){
        s16x8 af[2];
        #pragma unroll
        for(int pf=0;pf<2;++pf){
          s16x8 t = *(const s16x8*)(ar[pf] + kc*32);
          af[pf] = av[pf] ? t : (s16x8)0;
        }
        s16x8 bfr[4];
        #pragma unroll
        for(int cf=0;cf<4;++cf)
          bfr[cf] = *(const s16x8*)(wtap + (size_t)cf*16*K + kc*32);
        #pragma unroll
        for(int pf=0;pf<2;++pf)
          #pragma unroll
          for(int cf=0;cf<4;++cf)
            acc[pf][cf] = __builtin_amdgcn_mfma_f32_16x16x32_bf16(af[pf], bfr[cf], acc[pf][cf],0,0,0);
      }
    }
  }
  #pragma unroll
  for(int cf=0;cf<4;++cf){
    int co = cob + cf*16 + lr;
    float sc = g[co]*rsqrtf(vv[co]+EPS);
    float sh = be[co] - mm[co]*sc;
    if(bias) sh += bias[co]*sc;
    #pragma unroll
    for(int pf=0;pf<2;++pf){
      #pragma unroll
      for(int r=0;r<4;++r){
        int pix = mb + pf*16 + gq*4 + r;
        float v_ = acc[pf][cf][r]*sc + sh;
        out[((size_t)b*4096 + pix)*128 + co] = f2b(lrelu(v_));
      }
    }
  }
}

// ---------- fused q,k projection: D[pix, 0..127] = x2b @ [Wq|Wk]^T + [bq|bk]
__global__ __launch_bounds__(128) void k_projqk(
  const u16* __restrict__ x2b, const u16* __restrict__ wqk,
  const float* __restrict__ bq, const float* __restrict__ bk,
  u16* __restrict__ qbf, u16* __restrict__ kbf)
{
  int blk = blockIdx.x;           // 512 = 256 mt x 2 nt
  int nt = blk & 1;
  int mt = blk >> 1;
  int wid = threadIdx.x>>6, lane = threadIdx.x&63;
  int gq=lane>>4, lr=lane&15, g8=gq*8;
  int mb = mt*64 + wid*32;        // global pixel (b*4096+p)
  int cob = nt*64;
  f32x4 acc[2][4];
  #pragma unroll
  for(int pf=0;pf<2;++pf)
    #pragma unroll
    for(int cf=0;cf<4;++cf) acc[pf][cf]=(f32x4)0.f;
  const u16* xr0 = x2b + (size_t)(mb+lr)*128 + g8;
  const u16* xr1 = x2b + (size_t)(mb+16+lr)*128 + g8;
  const u16* wr  = wqk + (size_t)(cob+lr)*128 + g8;
  #pragma unroll
  for(int kc=0;kc<4;++kc){
    s16x8 a0 = *(const s16x8*)(xr0 + kc*32);
    s16x8 a1 = *(const s16x8*)(xr1 + kc*32);
    s16x8 bfr[4];
    #pragma unroll
    for(int cf=0;cf<4;++cf) bfr[cf] = *(const s16x8*)(wr + (size_t)cf*16*128 + kc*32);
    #pragma unroll
    for(int cf=0;cf<4;++cf){
      acc[0][cf] = __builtin_amdgcn_mfma_f32_16x16x32_bf16(a0, bfr[cf], acc[0][cf],0,0,0);
      acc[1][cf] = __builtin_amdgcn_mfma_f32_16x16x32_bf16(a1, bfr[cf], acc[1][cf],0,0,0);
    }
  }
  #pragma unroll
  for(int cf=0;cf<4;++cf){
    int co = cob + cf*16 + lr;
    float bi = co<64 ? bq[co] : bk[co-64];
    #pragma unroll
    for(int pf=0;pf<2;++pf){
      #pragma unroll
      for(int r=0;r<4;++r){
        int pix = mb + pf*16 + gq*4 + r;
        float v_ = acc[pf][cf][r] + bi;
        if(co<64) qbf[(size_t)pix*64 + co] = f2b(v_);
        else      kbf[(size_t)pix*64 + (co-64)] = f2b(v_);
      }
    }
  }
}

// ---------- v projection, transposed output: vbf[b][co][pix]
__global__ __launch_bounds__(128) void k_projv(
  const u16* __restrict__ x2b, const u16* __restrict__ wv,
  const float* __restrict__ bv, u16* __restrict__ vbf)
{
  int blk = blockIdx.x;      // 512 = 4 cot x 32 pt x 4 b
  int cot = blk & 3;
  int pt  = (blk>>2) & 31;
  int b   = blk >> 7;
  int wid = threadIdx.x>>6, lane = threadIdx.x&63;
  int gq=lane>>4, lr=lane&15, g8=gq*8;
  int cb = cot*32;
  int nb = pt*128 + wid*64;
  f32x4 acc[2][4];
  #pragma unroll
  for(int pf=0;pf<2;++pf)
    #pragma unroll
    for(int cf=0;cf<4;++cf) acc[pf][cf]=(f32x4)0.f;
  const u16* ar0 = wv + (size_t)(cb+lr)*128 + g8;
  const u16* ar1 = wv + (size_t)(cb+16+lr)*128 + g8;
  const u16* xr  = x2b + ((size_t)b*4096 + nb + lr)*128 + g8;
  #pragma unroll
  for(int kc=0;kc<4;++kc){
    s16x8 a0 = *(const s16x8*)(ar0+kc*32);
    s16x8 a1 = *(const s16x8*)(ar1+kc*32);
    s16x8 bfr[4];
    #pragma unroll
    for(int cf=0;cf<4;++cf) bfr[cf] = *(const s16x8*)(xr + (size_t)cf*16*128 + kc*32);
    #pragma unroll
    for(int cf=0;cf<4;++cf){
      acc[0][cf] = __builtin_amdgcn_mfma_f32_16x16x32_bf16(a0, bfr[cf], acc[0][cf],0,0,0);
      acc[1][cf] = __builtin_amdgcn_mfma_f32_16x16x32_bf16(a1, bfr[cf], acc[1][cf],0,0,0);
    }
  }
  #pragma unroll
  for(int pf=0;pf<2;++pf){
    #pragma unroll
    for(int r=0;r<4;++r){
      int co = cb + pf*16 + gq*4 + r;
      float bi = bv[co];
      #pragma unroll
      for(int cf=0;cf<4;++cf){
        int pix = nb + cf*16 + lr;
        vbf[((size_t)b*128+co)*4096 + pix] = f2b(acc[pf][cf][r] + bi);
      }
    }
  }
}

// ---------- MFMA flash attention + residual(+x2) + residual(+identity) + lrelu
// 2 waves/block, wave = 16 q-rows; grid 512
__global__ __launch_bounds__(128) void k_fattn(
    const u16* __restrict__ qbf, const u16* __restrict__ kbf,
    const u16* __restrict__ vbf, const u16* __restrict__ x2b,
    const u16* __restrict__ idbb, float* __restrict__ out){
  __shared__ u16 pl[2][1024];
  int wid = threadIdx.x>>6, lane = threadIdx.x&63;
  int gq = lane>>4, lr = lane&15;
  int b = blockIdx.x>>7, mt = blockIdx.x&127;
  int mbase = mt*32 + wid*16;

  const u16* qp = qbf + ((size_t)b*4096 + mbase + lr)*64 + gq*8;
  s16x8 qf0 = *(const s16x8*)qp;
  s16x8 qf1 = *(const s16x8*)(qp + 32);

  f32x4 acc[8];
  #pragma unroll
  for(int i=0;i<8;++i) acc[i] = (f32x4)0.f;
  float mrun = -3.0e38f, lrun = 0.f;

  const u16* kb0 = kbf + (size_t)b*4096*64 + (size_t)lr*64 + gq*8;
  const u16* vb0 = vbf + ((size_t)b*128 + lr)*4096 + gq*8;
  u16* pw = pl[wid];
  u32 swz = ((u32)(lr & 7)) << 4;
  u32 wb[4];
  #pragma unroll
  for(int nf=0;nf<4;++nf) wb[nf] = ((u32)((lr*64 + nf*16 + gq*4)*2)) ^ swz;
  u32 rb0 = ((u32)((lr*64 + gq*8)*2)) ^ swz;
  u32 rb1 = ((u32)((lr*64 + 32 + gq*8)*2)) ^ swz;

  for(int nt=0; nt<64; ++nt){
    const u16* kp = kb0 + (size_t)nt*64*64;
    f32x4 sf[4];
    #pragma unroll
    for(int nf=0;nf<4;++nf){
      s16x8 ka0 = *(const s16x8*)(kp + nf*16*64);
      s16x8 ka1 = *(const s16x8*)(kp + nf*16*64 + 32);
      f32x4 z = (f32x4)0.f;
      z = __builtin_amdgcn_mfma_f32_16x16x32_bf16(ka0, qf0, z, 0, 0, 0);
      z = __builtin_amdgcn_mfma_f32_16x16x32_bf16(ka1, qf1, z, 0, 0, 0);
      sf[nf] = z;
    }
    float tm = -3.0e38f;
    #pragma unroll
    for(int nf=0;nf<4;++nf){
      #pragma unroll
      for(int r=0;r<4;++r) tm = fmaxf(tm, sf[nf][r]);
    }
    tm = fmaxf(tm, __shfl_xor(tm, 16));
    tm = fmaxf(tm, __shfl_xor(tm, 32));
    float mnew = fmaxf(mrun, tm);
    float alpha = __expf(mrun - mnew);
    float ps = 0.f;
    #pragma unroll
    for(int nf=0;nf<4;++nf){
      #pragma unroll
      for(int r=0;r<4;++r){ float p = __expf(sf[nf][r] - mnew); sf[nf][r] = p; ps += p; }
    }
    ps += __shfl_xor(ps, 16);
    ps += __shfl_xor(ps, 32);
    lrun = lrun*alpha + ps;
    mrun = mnew;
    #pragma unroll
    for(int i=0;i<8;++i) acc[i] *= alpha;
    #pragma unroll
    for(int nf=0;nf<4;++nf){
      u32 lo = (u32)f2b(sf[nf][0]) | ((u32)f2b(sf[nf][1]) << 16);
      u32 hi = (u32)f2b(sf[nf][2]) | ((u32)f2b(sf[nf][3]) << 16);
      uint2 wv; wv.x = lo; wv.y = hi;
      *(uint2*)((char*)pw + wb[nf]) = wv;
    }
    s16x8 pb0 = *(const s16x8*)((char*)pw + rb0);
    s16x8 pb1 = *(const s16x8*)((char*)pw + rb1);
    const u16* vp = vb0 + nt*64;
    #pragma unroll
    for(int cf=0;cf<8;++cf){
      s16x8 va0 = *(const s16x8*)(vp + (size_t)cf*16*4096);
      s16x8 va1 = *(const s16x8*)(vp + (size_t)cf*16*4096 + 32);
      acc[cf] = __builtin_amdgcn_mfma_f32_16x16x32_bf16(va0, pb0, acc[cf], 0, 0, 0);
      acc[cf] = __builtin_amdgcn_mfma_f32_16x16x32_bf16(va1, pb1, acc[cf], 0, 0, 0);
    }
  }
  float inv = 1.f/lrun;
  int m = mbase + lr;
  size_t rbase = ((size_t)b*4096 + m)*128;
  size_t obase = ((size_t)b*128)*4096 + m;
  #pragma unroll
  for(int cf=0;cf<8;++cf){
    int c0 = cf*16 + gq*4;
    s16x4 xr = *(const s16x4*)(x2b + rbase + c0);
    s16x4 ir = *(const s16x4*)(idbb + rbase + c0);
    #pragma unroll
    for(int r=0;r<4;++r){
      float val = acc[cf][r]*inv + b2f(xr[r]) + b2f(ir[r]);
      out[obase + (size_t)(c0+r)*4096] = lrelu(val);
    }
  }
}

extern "C" void kernel_launch(void* const* d_in, const int* in_sizes, int n_in,
                              void* d_out, int out_size, void* d_ws, size_t ws_size,
                              hipStream_t stream) {
  const float* x    = (const float*)d_in[0];
  const float* W_up = (const float*)d_in[1];
  const float* b_up = (const float*)d_in[2];
  const float* g0   = (const float*)d_in[3];
  const float* be0  = (const float*)d_in[4];
  const float* m0   = (const float*)d_in[5];
  const float* v0   = (const float*)d_in[6];
  const float* W_r0 = (const float*)d_in[7];
  const float* g1   = (const float*)d_in[8];
  const float* be1  = (const float*)d_in[9];
  const float* m1   = (const float*)d_in[10];
  const float* v1   = (const float*)d_in[11];
  const float* W_r1 = (const float*)d_in[12];
  const float* g2   = (const float*)d_in[13];
  const float* be2  = (const float*)d_in[14];
  const float* m2   = (const float*)d_in[15];
  const float* v2   = (const float*)d_in[16];
  const float* Wq   = (const float*)d_in[17];
  const float* bq   = (const float*)d_in[18];
  const float* Wk   = (const float*)d_in[19];
  const float* bk   = (const float*)d_in[20];
  const float* Wv   = (const float*)d_in[21];
  const float* bv   = (const float*)d_in[22];

  float* ws = (float*)d_ws;
  u16* xh   = (u16*)(ws + 0);         // [4,1024,256]
  u16* ub   = (u16*)(ws + 524288);    // [4,4096,256]
  u16* idbb = (u16*)(ws + 2621440);   // [4,4096,128]
  u16* x1b  = (u16*)(ws + 3670016);   // [4,4096,128]
  u16* x2b  = (u16*)(ws + 4718592);   // [4,4096,128]
  u16* qbf  = (u16*)(ws + 5767168);   // [4,4096,64]
  u16* kbf  = (u16*)(ws + 6291456);   // [4,4096,64]
  u16* vbf  = (u16*)(ws + 6815744);   // [4,128,4096]
  u16* wtu  = (u16*)(ws + 7864320);   // [128,2304]
  u16* wtr0 = (u16*)(ws + 8011776);   // [128,1152]
  u16* wtr1 = (u16*)(ws + 8085504);   // [128,1152]
  u16* wqk  = (u16*)(ws + 8159232);   // [128,128]
  u16* wvb  = (u16*)(ws + 8167424);   // [128,128]
  float* out = (float*)d_out;

  // weight transforms
  k_wconv<256><<<1152, 256, 0, stream>>>(W_up, wtu);
  k_wconv<128><<<576, 256, 0, stream>>>(W_r0, wtr0);
  k_wconv<128><<<576, 256, 0, stream>>>(W_r1, wtr1);
  k_wproj<<<128, 256, 0, stream>>>(Wq, Wk, Wv, wqk, wvb);
  // input layout + upsample
  k_tr<<<1024, 256, 0, stream>>>(x, xh);
  k_up8<<<2048, 256, 0, stream>>>(xh, ub);
  // convs (MFMA implicit GEMM)
  k_cmfma<256><<<512, 128, 0, stream>>>(ub, wtu, b_up, g0, be0, m0, v0, idbb);
  k_cmfma<128><<<512, 128, 0, stream>>>(idbb, wtr0, nullptr, g1, be1, m1, v1, x1b);
  k_cmfma<128><<<512, 128, 0, stream>>>(x1b, wtr1, nullptr, g2, be2, m2, v2, x2b);
  // projections
  k_projqk<<<512, 128, 0, stream>>>(x2b, wqk, bq, bk, qbf, kbf);
  k_projv<<<512, 128, 0, stream>>>(x2b, wvb, bv, vbf);
  // attention + residuals + lrelu
  k_fattn<<<512, 128, 0, stream>>>(qbf, kbf, vbf, x2b, idbb, out);
}

// Round 4
// 235.218 us; speedup vs baseline: 14.1995x; 1.5705x over previous
//
#include <hip/hip_runtime.h>
#include <math.h>

#define EPS 1e-5f
#define SLOPE 0.2f

typedef unsigned short u16;
typedef unsigned int u32;
typedef __attribute__((ext_vector_type(4))) float f32x4;
typedef __attribute__((ext_vector_type(8))) short s16x8;
typedef __attribute__((ext_vector_type(4))) short s16x4;

__device__ __forceinline__ float lrelu(float x){ return x >= 0.f ? x : SLOPE*x; }

// f32 -> bf16 bits, round-to-nearest-even
__device__ __forceinline__ u16 f2b(float x){
  u32 u = __float_as_uint(x);
  u32 r = (u + 0x7FFFu + ((u >> 16) & 1u)) >> 16;
  return (u16)r;
}
__device__ __forceinline__ float b2f(short v){
  return __uint_as_float(((u32)(u16)v) << 16);
}

// ---------- NCHW f32 [4,256,32,32] -> NHWC bf16 [4,1024,256] (LDS transpose)
__global__ void k_tr(const float* __restrict__ x, u16* __restrict__ xh){
  __shared__ float t[32][33];
  int b = blockIdx.x>>8; int c0 = ((blockIdx.x>>5)&7)*32; int p0 = (blockIdx.x&31)*32;
  int tx = threadIdx.x&31, ty = threadIdx.x>>5;   // 32 x 8
  #pragma unroll
  for(int r=0;r<32;r+=8)
    t[ty+r][tx] = x[((size_t)(b*256 + c0+ty+r))*1024 + p0 + tx];
  __syncthreads();
  #pragma unroll
  for(int r=0;r<32;r+=8)
    xh[((size_t)(b*1024 + p0+ty+r))*256 + c0 + tx] = f2b(t[tx][ty+r]);
}

// ---------- bilinear x2 upsample (align_corners) NHWC bf16
__global__ void k_up8(const u16* __restrict__ xh, u16* __restrict__ u){
  int idx = blockIdx.x*256 + threadIdx.x;    // 524288 total (8 ch per thread)
  int cg = idx & 31;
  int ow = (idx>>5) & 63; int oh = (idx>>11)&63; int b = idx>>17;
  const float st = 31.0f/63.0f;
  float fh = oh*st, fw = ow*st;
  int h0=(int)fh, w0=(int)fw;
  float wh = fh-(float)h0, ww = fw-(float)w0;
  int h1=min(h0+1,31), w1=min(w0+1,31);
  const u16* xb = xh + ((size_t)b*1024)*256 + cg*8;
  s16x8 a = *(const s16x8*)(xb + (size_t)(h0*32+w0)*256);
  s16x8 bb= *(const s16x8*)(xb + (size_t)(h0*32+w1)*256);
  s16x8 c = *(const s16x8*)(xb + (size_t)(h1*32+w0)*256);
  s16x8 d = *(const s16x8*)(xb + (size_t)(h1*32+w1)*256);
  u16 o[8];
  #pragma unroll
  for(int j=0;j<8;++j){
    float top = b2f(a[j]) + (b2f(bb[j])-b2f(a[j]))*ww;
    float bot = b2f(c[j]) + (b2f(d[j])-b2f(c[j]))*ww;
    o[j] = f2b(top + (bot-top)*wh);
  }
  *(s16x8*)(u + (size_t)idx*8) = *(s16x8*)o;
}

// ---------- conv weight transform: OIHW f32 -> [co][tap*Cin+ci] bf16
template<int CIN>
__global__ void k_wconv(const float* __restrict__ W, u16* __restrict__ wt){
  int idx = blockIdx.x*256 + threadIdx.x;
  int ci = idx & (CIN-1);
  int t2 = idx / CIN;
  int tap = t2 % 9;
  int co = t2 / 9;
  wt[idx] = f2b(W[((size_t)co*CIN + ci)*9 + tap]);
}

// ---------- projection weight transform
__global__ void k_wproj(const float* __restrict__ Wq, const float* __restrict__ Wk,
                        const float* __restrict__ Wv, u16* __restrict__ wqk,
                        u16* __restrict__ wv){
  int idx = blockIdx.x*256 + threadIdx.x;
  if(idx < 16384){
    float v_ = idx < 8192 ? Wq[idx] : Wk[idx-8192];
    wqk[idx] = f2b(v_);
  } else {
    wv[idx-16384] = f2b(Wv[idx-16384]);
  }
}

// ---------- implicit-GEMM 3x3 conv (MFMA) + BN + LReLU, NHWC bf16
template<int CIN>
__global__ __launch_bounds__(128) void k_cmfma(
    const u16* __restrict__ xin, const u16* __restrict__ wt,
    const float* __restrict__ bias,
    const float* __restrict__ g, const float* __restrict__ be,
    const float* __restrict__ mm, const float* __restrict__ vv,
    u16* __restrict__ out)
{
  constexpr int K = CIN*9;
  int blk = blockIdx.x;
  int mt = blk & 63;
  int nt = (blk>>6) & 1;
  int b  = blk >> 7;
  int wid = threadIdx.x>>6, lane = threadIdx.x&63;
  int gq = lane>>4, lr = lane&15;
  int g8 = gq*8;
  int mb = mt*64 + wid*32;
  int h = mb>>6, w0 = mb&63;
  int cob = nt*64;

  f32x4 acc[2][4];
  #pragma unroll
  for(int pf=0;pf<2;++pf)
    #pragma unroll
    for(int cf=0;cf<4;++cf) acc[pf][cf]=(f32x4)0.f;

  const u16* xb = xin + (size_t)b*4096*CIN;
  const u16* wr = wt + (size_t)(cob+lr)*K + g8;

  for(int dy=-1; dy<=1; ++dy){
    int hh = h+dy;
    if(hh<0 || hh>63) continue;
    #pragma unroll
    for(int dx=-1; dx<=1; ++dx){
      int tap = (dy+1)*3 + (dx+1);
      const u16* wtap = wr + tap*CIN;
      const u16* ar[2]; bool av[2];
      #pragma unroll
      for(int pf=0;pf<2;++pf){
        int ww = w0 + pf*16 + lr + dx;
        av[pf] = (ww>=0)&&(ww<64);
        int wc = ww<0?0:(ww>63?63:ww);
        ar[pf] = xb + ((size_t)hh*64 + wc)*CIN + g8;
      }
      #pragma unroll
      for(int kc=0;kc<CIN/32;++kc){
        s16x8 af[2];
        #pragma unroll
        for(int pf=0;pf<2;++pf){
          s16x8 t = *(const s16x8*)(ar[pf] + kc*32);
          af[pf] = av[pf] ? t : (s16x8)0;
        }
        s16x8 bfr[4];
        #pragma unroll
        for(int cf=0;cf<4;++cf)
          bfr[cf] = *(const s16x8*)(wtap + (size_t)cf*16*K + kc*32);
        #pragma unroll
        for(int pf=0;pf<2;++pf)
          #pragma unroll
          for(int cf=0;cf<4;++cf)
            acc[pf][cf] = __builtin_amdgcn_mfma_f32_16x16x32_bf16(af[pf], bfr[cf], acc[pf][cf],0,0,0);
      }
    }
  }
  #pragma unroll
  for(int cf=0;cf<4;++cf){
    int co = cob + cf*16 + lr;
    float sc = g[co]*rsqrtf(vv[co]+EPS);
    float sh = be[co] - mm[co]*sc;
    if(bias) sh += bias[co]*sc;
    #pragma unroll
    for(int pf=0;pf<2;++pf){
      #pragma unroll
      for(int r=0;r<4;++r){
        int pix = mb + pf*16 + gq*4 + r;
        float v_ = acc[pf][cf][r]*sc + sh;
        out[((size_t)b*4096 + pix)*128 + co] = f2b(lrelu(v_));
      }
    }
  }
}

// ---------- fused q,k projection
__global__ __launch_bounds__(128) void k_projqk(
  const u16* __restrict__ x2b, const u16* __restrict__ wqk,
  const float* __restrict__ bq, const float* __restrict__ bk,
  u16* __restrict__ qbf, u16* __restrict__ kbf)
{
  int blk = blockIdx.x;           // 512 = 256 mt x 2 nt
  int nt = blk & 1;
  int mt = blk >> 1;
  int wid = threadIdx.x>>6, lane = threadIdx.x&63;
  int gq=lane>>4, lr=lane&15, g8=gq*8;
  int mb = mt*64 + wid*32;
  int cob = nt*64;
  f32x4 acc[2][4];
  #pragma unroll
  for(int pf=0;pf<2;++pf)
    #pragma unroll
    for(int cf=0;cf<4;++cf) acc[pf][cf]=(f32x4)0.f;
  const u16* xr0 = x2b + (size_t)(mb+lr)*128 + g8;
  const u16* xr1 = x2b + (size_t)(mb+16+lr)*128 + g8;
  const u16* wr  = wqk + (size_t)(cob+lr)*128 + g8;
  #pragma unroll
  for(int kc=0;kc<4;++kc){
    s16x8 a0 = *(const s16x8*)(xr0 + kc*32);
    s16x8 a1 = *(const s16x8*)(xr1 + kc*32);
    s16x8 bfr[4];
    #pragma unroll
    for(int cf=0;cf<4;++cf) bfr[cf] = *(const s16x8*)(wr + (size_t)cf*16*128 + kc*32);
    #pragma unroll
    for(int cf=0;cf<4;++cf){
      acc[0][cf] = __builtin_amdgcn_mfma_f32_16x16x32_bf16(a0, bfr[cf], acc[0][cf],0,0,0);
      acc[1][cf] = __builtin_amdgcn_mfma_f32_16x16x32_bf16(a1, bfr[cf], acc[1][cf],0,0,0);
    }
  }
  #pragma unroll
  for(int cf=0;cf<4;++cf){
    int co = cob + cf*16 + lr;
    float bi = co<64 ? bq[co] : bk[co-64];
    #pragma unroll
    for(int pf=0;pf<2;++pf){
      #pragma unroll
      for(int r=0;r<4;++r){
        int pix = mb + pf*16 + gq*4 + r;
        float v_ = acc[pf][cf][r] + bi;
        if(co<64) qbf[(size_t)pix*64 + co] = f2b(v_);
        else      kbf[(size_t)pix*64 + (co-64)] = f2b(v_);
      }
    }
  }
}

// ---------- v projection, transposed output: vbf[b][co][pix]
__global__ __launch_bounds__(128) void k_projv(
  const u16* __restrict__ x2b, const u16* __restrict__ wv,
  const float* __restrict__ bv, u16* __restrict__ vbf)
{
  int blk = blockIdx.x;      // 512 = 4 cot x 32 pt x 4 b
  int cot = blk & 3;
  int pt  = (blk>>2) & 31;
  int b   = blk >> 7;
  int wid = threadIdx.x>>6, lane = threadIdx.x&63;
  int gq=lane>>4, lr=lane&15, g8=gq*8;
  int cb = cot*32;
  int nb = pt*128 + wid*64;
  f32x4 acc[2][4];
  #pragma unroll
  for(int pf=0;pf<2;++pf)
    #pragma unroll
    for(int cf=0;cf<4;++cf) acc[pf][cf]=(f32x4)0.f;
  const u16* ar0 = wv + (size_t)(cb+lr)*128 + g8;
  const u16* ar1 = wv + (size_t)(cb+16+lr)*128 + g8;
  const u16* xr  = x2b + ((size_t)b*4096 + nb + lr)*128 + g8;
  #pragma unroll
  for(int kc=0;kc<4;++kc){
    s16x8 a0 = *(const s16x8*)(ar0+kc*32);
    s16x8 a1 = *(const s16x8*)(ar1+kc*32);
    s16x8 bfr[4];
    #pragma unroll
    for(int cf=0;cf<4;++cf) bfr[cf] = *(const s16x8*)(xr + (size_t)cf*16*128 + kc*32);
    #pragma unroll
    for(int cf=0;cf<4;++cf){
      acc[0][cf] = __builtin_amdgcn_mfma_f32_16x16x32_bf16(a0, bfr[cf], acc[0][cf],0,0,0);
      acc[1][cf] = __builtin_amdgcn_mfma_f32_16x16x32_bf16(a1, bfr[cf], acc[1][cf],0,0,0);
    }
  }
  #pragma unroll
  for(int pf=0;pf<2;++pf){
    #pragma unroll
    for(int r=0;r<4;++r){
      int co = cb + pf*16 + gq*4 + r;
      float bi = bv[co];
      #pragma unroll
      for(int cf=0;cf<4;++cf){
        int pix = nb + cf*16 + lr;
        vbf[((size_t)b*128+co)*4096 + pix] = f2b(acc[pf][cf][r] + bi);
      }
    }
  }
}

// ---------- MFMA flash attention, KV-split x4, 32 q-rows/wave
// block = 4 waves (256 thr); wave w handles KV tiles [w*16, w*16+16) for the
// block's 32 q-rows; LDS combine merges the 4 online-softmax partials.
// grid 512: xcd-aware mapping -> batch b = (blk&7)>>1 (one batch per 2 XCDs)
__global__ __launch_bounds__(256) void k_fattn2(
    const u16* __restrict__ qbf, const u16* __restrict__ kbf,
    const u16* __restrict__ vbf, const u16* __restrict__ x2b,
    const u16* __restrict__ idbb, float* __restrict__ out){
  __shared__ float smem[16384 + 256];   // 64KB acc-dump (aliased P bounce) + stats
  float* sst = smem + 16384;            // [w][pf][lr][2]
  int wid = threadIdx.x>>6, lane = threadIdx.x&63;
  int gq = lane>>4, lr = lane&15;
  int blk = blockIdx.x;
  int b  = (blk&7)>>1;
  int mt = ((blk>>3)<<1) | (blk&1);     // 0..127
  int mbase = mt*32;

  // Q B-fragments, 2 m-frags (rows mbase+lr, mbase+16+lr)
  const u16* qp = qbf + ((size_t)b*4096 + mbase + lr)*64 + gq*8;
  s16x8 qf[2][2];
  qf[0][0] = *(const s16x8*)qp;
  qf[0][1] = *(const s16x8*)(qp + 32);
  qf[1][0] = *(const s16x8*)(qp + 16*64);
  qf[1][1] = *(const s16x8*)(qp + 16*64 + 32);

  f32x4 acc[2][8];
  #pragma unroll
  for(int pf=0;pf<2;++pf)
    #pragma unroll
    for(int i=0;i<8;++i) acc[pf][i] = (f32x4)0.f;
  float mrun[2] = {-3.0e38f, -3.0e38f}, lrun[2] = {0.f, 0.f};

  const u16* kb0 = kbf + (size_t)b*4096*64 + (size_t)lr*64 + gq*8;
  const u16* vb0 = vbf + ((size_t)b*128 + lr)*4096 + gq*8;

  // wave-private P bounce (aliases the acc-dump region; re-used after loop)
  u16* pw = (u16*)(smem + wid*4096);
  u32 swz = ((u32)(lr & 7)) << 4;
  u32 wb[4];
  #pragma unroll
  for(int nf=0;nf<4;++nf) wb[nf] = ((u32)((lr*64 + nf*16 + gq*4)*2)) ^ swz;
  u32 rb0 = ((u32)((lr*64 + gq*8)*2)) ^ swz;
  u32 rb1 = ((u32)((lr*64 + 32 + gq*8)*2)) ^ swz;

  for(int t=0; t<16; ++t){
    int nt = wid*16 + t;
    const u16* kp = kb0 + (size_t)nt*64*64;
    f32x4 sf[2][4];
    #pragma unroll
    for(int nf=0;nf<4;++nf){
      s16x8 ka0 = *(const s16x8*)(kp + nf*16*64);
      s16x8 ka1 = *(const s16x8*)(kp + nf*16*64 + 32);
      #pragma unroll
      for(int pf=0;pf<2;++pf){
        f32x4 z = (f32x4)0.f;
        z = __builtin_amdgcn_mfma_f32_16x16x32_bf16(ka0, qf[pf][0], z, 0, 0, 0);
        z = __builtin_amdgcn_mfma_f32_16x16x32_bf16(ka1, qf[pf][1], z, 0, 0, 0);
        sf[pf][nf] = z;
      }
    }
    #pragma unroll
    for(int pf=0;pf<2;++pf){
      float tm = -3.0e38f;
      #pragma unroll
      for(int nf=0;nf<4;++nf)
        #pragma unroll
        for(int r=0;r<4;++r) tm = fmaxf(tm, sf[pf][nf][r]);
      tm = fmaxf(tm, __shfl_xor(tm, 16));
      tm = fmaxf(tm, __shfl_xor(tm, 32));
      float mnew = fmaxf(mrun[pf], tm);
      float alpha = __expf(mrun[pf] - mnew);
      float ps = 0.f;
      #pragma unroll
      for(int nf=0;nf<4;++nf)
        #pragma unroll
        for(int r=0;r<4;++r){ float p = __expf(sf[pf][nf][r] - mnew); sf[pf][nf][r] = p; ps += p; }
      ps += __shfl_xor(ps, 16);
      ps += __shfl_xor(ps, 32);
      lrun[pf] = lrun[pf]*alpha + ps;
      mrun[pf] = mnew;
      #pragma unroll
      for(int i=0;i<8;++i) acc[pf][i] *= alpha;
      // P -> LDS bf16 (wave-private, swizzled)
      #pragma unroll
      for(int nf=0;nf<4;++nf){
        u32 lo = (u32)f2b(sf[pf][nf][0]) | ((u32)f2b(sf[pf][nf][1]) << 16);
        u32 hi = (u32)f2b(sf[pf][nf][2]) | ((u32)f2b(sf[pf][nf][3]) << 16);
        uint2 wv; wv.x = lo; wv.y = hi;
        *(uint2*)((char*)pw + (pf*2048 + wb[nf])) = wv;
      }
    }
    s16x8 pb[2][2];
    #pragma unroll
    for(int pf=0;pf<2;++pf){
      pb[pf][0] = *(const s16x8*)((char*)pw + (pf*2048 + rb0));
      pb[pf][1] = *(const s16x8*)((char*)pw + (pf*2048 + rb1));
    }
    const u16* vp = vb0 + nt*64;
    #pragma unroll
    for(int cf=0;cf<8;++cf){
      s16x8 va0 = *(const s16x8*)(vp + (size_t)cf*16*4096);
      s16x8 va1 = *(const s16x8*)(vp + (size_t)cf*16*4096 + 32);
      #pragma unroll
      for(int pf=0;pf<2;++pf){
        acc[pf][cf] = __builtin_amdgcn_mfma_f32_16x16x32_bf16(va0, pb[pf][0], acc[pf][cf], 0, 0, 0);
        acc[pf][cf] = __builtin_amdgcn_mfma_f32_16x16x32_bf16(va1, pb[pf][1], acc[pf][cf], 0, 0, 0);
      }
    }
  }

  // dump partials (overwrites P bounce region — same wave, safe)
  if(gq == 0){
    #pragma unroll
    for(int pf=0;pf<2;++pf){
      sst[((wid*2+pf)*16 + lr)*2 + 0] = mrun[pf];
      sst[((wid*2+pf)*16 + lr)*2 + 1] = lrun[pf];
    }
  }
  #pragma unroll
  for(int pf=0;pf<2;++pf)
    #pragma unroll
    for(int cf=0;cf<8;++cf)
      *(f32x4*)(smem + wid*4096 + (pf*8+cf)*256 + lane*4) = acc[pf][cf];
  __syncthreads();

  // combine: wave wid handles ids wid*4 .. wid*4+3  (id = pf*8+cf)
  #pragma unroll
  for(int q_=0;q_<4;++q_){
    int id = wid*4 + q_;
    int pf = id>>3, cf = id&7;
    float mw[4], lw[4], Mx = -3.0e38f;
    #pragma unroll
    for(int w=0;w<4;++w){
      mw[w] = sst[((w*2+pf)*16 + lr)*2 + 0];
      lw[w] = sst[((w*2+pf)*16 + lr)*2 + 1];
      Mx = fmaxf(Mx, mw[w]);
    }
    float lstar = 0.f;
    f32x4 O = (f32x4)0.f;
    #pragma unroll
    for(int w=0;w<4;++w){
      float sw = __expf(mw[w] - Mx);
      lstar += lw[w]*sw;
      f32x4 aw = *(const f32x4*)(smem + w*4096 + id*256 + lane*4);
      O += sw * aw;
    }
    float inv = 1.f/lstar;
    int m = mbase + pf*16 + lr;
    int c0 = cf*16 + gq*4;
    size_t rbase = ((size_t)b*4096 + m)*128 + c0;
    s16x4 xr = *(const s16x4*)(x2b + rbase);
    s16x4 ir = *(const s16x4*)(idbb + rbase);
    #pragma unroll
    for(int r=0;r<4;++r){
      float val = O[r]*inv + b2f(xr[r]) + b2f(ir[r]);
      out[((size_t)b*128 + c0 + r)*4096 + m] = lrelu(val);
    }
  }
}

extern "C" void kernel_launch(void* const* d_in, const int* in_sizes, int n_in,
                              void* d_out, int out_size, void* d_ws, size_t ws_size,
                              hipStream_t stream) {
  const float* x    = (const float*)d_in[0];
  const float* W_up = (const float*)d_in[1];
  const float* b_up = (const float*)d_in[2];
  const float* g0   = (const float*)d_in[3];
  const float* be0  = (const float*)d_in[4];
  const float* m0   = (const float*)d_in[5];
  const float* v0   = (const float*)d_in[6];
  const float* W_r0 = (const float*)d_in[7];
  const float* g1   = (const float*)d_in[8];
  const float* be1  = (const float*)d_in[9];
  const float* m1   = (const float*)d_in[10];
  const float* v1   = (const float*)d_in[11];
  const float* W_r1 = (const float*)d_in[12];
  const float* g2   = (const float*)d_in[13];
  const float* be2  = (const float*)d_in[14];
  const float* m2   = (const float*)d_in[15];
  const float* v2   = (const float*)d_in[16];
  const float* Wq   = (const float*)d_in[17];
  const float* bq   = (const float*)d_in[18];
  const float* Wk   = (const float*)d_in[19];
  const float* bk   = (const float*)d_in[20];
  const float* Wv   = (const float*)d_in[21];
  const float* bv   = (const float*)d_in[22];

  float* ws = (float*)d_ws;
  u16* xh   = (u16*)(ws + 0);         // [4,1024,256]
  u16* ub   = (u16*)(ws + 524288);    // [4,4096,256]
  u16* idbb = (u16*)(ws + 2621440);   // [4,4096,128]
  u16* x1b  = (u16*)(ws + 3670016);   // [4,4096,128]
  u16* x2b  = (u16*)(ws + 4718592);   // [4,4096,128]
  u16* qbf  = (u16*)(ws + 5767168);   // [4,4096,64]
  u16* kbf  = (u16*)(ws + 6291456);   // [4,4096,64]
  u16* vbf  = (u16*)(ws + 6815744);   // [4,128,4096]
  u16* wtu  = (u16*)(ws + 7864320);   // [128,2304]
  u16* wtr0 = (u16*)(ws + 8011776);   // [128,1152]
  u16* wtr1 = (u16*)(ws + 8085504);   // [128,1152]
  u16* wqk  = (u16*)(ws + 8159232);   // [128,128]
  u16* wvb  = (u16*)(ws + 8167424);   // [128,128]
  float* out = (float*)d_out;

  // weight transforms
  k_wconv<256><<<1152, 256, 0, stream>>>(W_up, wtu);
  k_wconv<128><<<576, 256, 0, stream>>>(W_r0, wtr0);
  k_wconv<128><<<576, 256, 0, stream>>>(W_r1, wtr1);
  k_wproj<<<128, 256, 0, stream>>>(Wq, Wk, Wv, wqk, wvb);
  // input layout + upsample
  k_tr<<<1024, 256, 0, stream>>>(x, xh);
  k_up8<<<2048, 256, 0, stream>>>(xh, ub);
  // convs (MFMA implicit GEMM)
  k_cmfma<256><<<512, 128, 0, stream>>>(ub, wtu, b_up, g0, be0, m0, v0, idbb);
  k_cmfma<128><<<512, 128, 0, stream>>>(idbb, wtr0, nullptr, g1, be1, m1, v1, x1b);
  k_cmfma<128><<<512, 128, 0, stream>>>(x1b, wtr1, nullptr, g2, be2, m2, v2, x2b);
  // projections
  k_projqk<<<512, 128, 0, stream>>>(x2b, wqk, bq, bk, qbf, kbf);
  k_projv<<<512, 128, 0, stream>>>(x2b, wvb, bv, vbf);
  // attention + residuals + lrelu (KV-split x4)
  k_fattn2<<<512, 256, 0, stream>>>(qbf, kbf, vbf, x2b, idbb, out);
}